// Round 2
// baseline (309.290 us; speedup 1.0000x reference)
//
#include <hip/hip_runtime.h>

// B=512, P=64, K=8, D=512, T=50000
// out: [B*P, 2*D] fp32
#define BB 512
#define PP 64
#define KK 8
#define DD 512

typedef float v4f __attribute__((ext_vector_type(4)));

// ---------------------------------------------------------------------------
// Two-phase split WITHOUT workspace:
//   phase 1 reads only the inputs table (64 MB, L3-resident) -> logits,
//     softmax; writes focal half of out + stashes the 8 sim weights in the
//     first 32 B of the graph half of out (overwritten by phase 2).
//   phase 2 reads only the title table (102 MB, L3-resident by itself) ->
//     weighted title sum; overwrites the graph half.
// Avoiding d_ws keeps the harness's 512 MB workspace-poison fill out of the
// dispatch stream.
//
// MLP restructure: all 8 gather addresses are computed up front; masked slots
// are predicated to an L1-hot safe row (indices are always in-bounds by
// construction) so ALL 16 float4 gathers issue unconditionally and sit in
// flight together, instead of 16 serialized HBM round-trips at 28 VGPRs.
// ---------------------------------------------------------------------------

__global__ __launch_bounds__(256) void han_phase1(
    const float* __restrict__ inputs,       // [B,P,D]
    const int*   __restrict__ nbr_batch,    // [B,P,K]
    const int*   __restrict__ nbr_job,      // [B,P,K]
    const int*   __restrict__ nbr_mask,     // [B,P,K]
    float*       __restrict__ out)          // [B*P, 2*D]
{
    const int lane = threadIdx.x & 63;
    const int wave = threadIdx.x >> 6;
    const int row  = blockIdx.x * 4 + wave;        // in [0, B*P)

    // neighbor indices: 8 contiguous ints per row, 16B-aligned
    const int4* nb4 = (const int4*)(nbr_batch + row * KK);
    const int4* nj4 = (const int4*)(nbr_job   + row * KK);
    const int4* nm4 = (const int4*)(nbr_mask  + row * KK);
    int nbk[KK], njk[KK], nmk[KK];
    *(int4*)&nbk[0] = nb4[0]; *(int4*)&nbk[4] = nb4[1];
    *(int4*)&njk[0] = nj4[0]; *(int4*)&njk[4] = nj4[1];
    *(int4*)&nmk[0] = nm4[0]; *(int4*)&nmk[4] = nm4[1];

    // gather addresses; masked -> focal row (L1-hot, no extra HBM traffic)
    const float4* g4[KK];
    #pragma unroll
    for (int k = 0; k < KK; ++k) {
        const size_t r = nmk[k] ? ((size_t)nbk[k] * PP + (size_t)njk[k])
                                : (size_t)row;
        g4[k] = (const float4*)(inputs + r * DD);
    }

    // issue ALL loads (focal + 8 neighbor rows) before any arithmetic
    const float4* inp4 = (const float4*)(inputs + (size_t)row * DD);
    const float4 fa = inp4[lane];        // d = lane*4
    const float4 fb = inp4[lane + 64];   // d = 256 + lane*4
    float4 ga[KK], gb[KK];
    #pragma unroll
    for (int k = 0; k < KK; ++k) {
        ga[k] = g4[k][lane];
        gb[k] = g4[k][lane + 64];
    }

    // per-lane partial dots
    float d[KK];
    #pragma unroll
    for (int k = 0; k < KK; ++k) {
        d[k] = fa.x*ga[k].x + fa.y*ga[k].y + fa.z*ga[k].z + fa.w*ga[k].w
             + fb.x*gb[k].x + fb.y*gb[k].y + fb.z*gb[k].z + fb.w*gb[k].w;
    }

    // butterfly reduce all 8 dots together (independent shuffles pipeline)
    #pragma unroll
    for (int off = 32; off >= 1; off >>= 1) {
        #pragma unroll
        for (int k = 0; k < KK; ++k)
            d[k] += __shfl_xor(d[k], off, 64);
    }

    float logit[KK];
    #pragma unroll
    for (int k = 0; k < KK; ++k) logit[k] = nmk[k] ? d[k] : -1e9f;

    // masked softmax over K=8 (replicated per lane; all scalar)
    float m = logit[0];
    #pragma unroll
    for (int k = 1; k < KK; ++k) m = fmaxf(m, logit[k]);
    float e[KK];
    float s = 0.0f;
    #pragma unroll
    for (int k = 0; k < KK; ++k) {
        e[k] = expf(logit[k] - m);
        s += e[k];
    }
    const float inv = 1.0f / s;

    // focal half of out: write-once -> non-temporal
    v4f* o4 = (v4f*)(out + (size_t)row * (2 * DD));
    v4f va = {fa.x, fa.y, fa.z, fa.w};
    v4f vb = {fb.x, fb.y, fb.z, fb.w};
    __builtin_nontemporal_store(va, o4 + lane);        // d 0..255
    __builtin_nontemporal_store(vb, o4 + lane + 64);   // d 256..511

    // stash sim weights (exact 0 on masked slots) in the first 32 B of the
    // graph half; phase 2 reads them then overwrites the whole half.
    if (lane == 0) {
        float4* s4 = (float4*)(out + (size_t)row * (2 * DD) + DD);
        s4[0] = make_float4(nmk[0] ? e[0]*inv : 0.f,
                            nmk[1] ? e[1]*inv : 0.f,
                            nmk[2] ? e[2]*inv : 0.f,
                            nmk[3] ? e[3]*inv : 0.f);
        s4[1] = make_float4(nmk[4] ? e[4]*inv : 0.f,
                            nmk[5] ? e[5]*inv : 0.f,
                            nmk[6] ? e[6]*inv : 0.f,
                            nmk[7] ? e[7]*inv : 0.f);
    }
}

__global__ __launch_bounds__(256) void han_phase2(
    const float* __restrict__ title,        // [T,D]
    const int*   __restrict__ nbr_title,    // [B,P,K]
    const int*   __restrict__ nbr_mask,     // [B,P,K]
    float*       __restrict__ out)          // [B*P, 2*D]
{
    const int lane = threadIdx.x & 63;
    const int wave = threadIdx.x >> 6;
    const int row  = blockIdx.x * 4 + wave;

    const int4* nt4 = (const int4*)(nbr_title + row * KK);
    const int4* nm4 = (const int4*)(nbr_mask  + row * KK);
    int ntk[KK], nmk[KK];
    *(int4*)&ntk[0] = nt4[0]; *(int4*)&ntk[4] = nt4[1];
    *(int4*)&nmk[0] = nm4[0]; *(int4*)&nmk[4] = nm4[1];

    // gather addresses depend only on indices+mask (NOT on the weight load),
    // so all 16 title loads issue in parallel with the weight fetch.
    // masked -> title row 0 (permanently L2-hot across the whole grid).
    const float4* t4[KK];
    #pragma unroll
    for (int k = 0; k < KK; ++k) {
        const size_t r = nmk[k] ? (size_t)ntk[k] : (size_t)0;
        t4[k] = (const float4*)(title + r * DD);
    }

    float4 ta[KK], tb[KK];
    #pragma unroll
    for (int k = 0; k < KK; ++k) {
        ta[k] = t4[k][lane];
        tb[k] = t4[k][lane + 64];
    }

    // stashed sim weights (wave-uniform broadcast load; masked slots exact 0)
    const float4* s4 = (const float4*)(out + (size_t)row * (2 * DD) + DD);
    const float4 w0 = s4[0];
    const float4 w1 = s4[1];
    const float w[KK] = {w0.x, w0.y, w0.z, w0.w, w1.x, w1.y, w1.z, w1.w};

    // unconditional FMA: masked slots have w==0 exactly, 0 * finite == 0
    float4 oa = make_float4(0.f, 0.f, 0.f, 0.f);
    float4 ob = make_float4(0.f, 0.f, 0.f, 0.f);
    #pragma unroll
    for (int k = 0; k < KK; ++k) {
        oa.x += w[k]*ta[k].x; oa.y += w[k]*ta[k].y;
        oa.z += w[k]*ta[k].z; oa.w += w[k]*ta[k].w;
        ob.x += w[k]*tb[k].x; ob.y += w[k]*tb[k].y;
        ob.z += w[k]*tb[k].z; ob.w += w[k]*tb[k].w;
    }

    v4f* o4 = (v4f*)(out + (size_t)row * (2 * DD));
    v4f vc = {oa.x, oa.y, oa.z, oa.w};
    v4f vd = {ob.x, ob.y, ob.z, ob.w};
    __builtin_nontemporal_store(vc, o4 + lane + 128);  // graph 0..255
    __builtin_nontemporal_store(vd, o4 + lane + 192);  // graph 256..511
}

extern "C" void kernel_launch(void* const* d_in, const int* in_sizes, int n_in,
                              void* d_out, int out_size, void* d_ws, size_t ws_size,
                              hipStream_t stream) {
    const float* inputs    = (const float*)d_in[0];
    const float* title     = (const float*)d_in[1];
    const int*   nbr_batch = (const int*)d_in[2];
    const int*   nbr_job   = (const int*)d_in[3];
    const int*   nbr_title = (const int*)d_in[4];
    const int*   nbr_mask  = (const int*)d_in[5];
    float*       out       = (float*)d_out;

    const int rows = BB * PP;     // 32768
    dim3 grid(rows / 4);          // 4 waves (rows) per 256-thread block
    dim3 block(256);

    han_phase1<<<grid, block, 0, stream>>>(
        inputs, nbr_batch, nbr_job, nbr_mask, out);
    han_phase2<<<grid, block, 0, stream>>>(
        title, nbr_title, nbr_mask, out);
}

// Round 3
// 299.722 us; speedup vs baseline: 1.0319x; 1.0319x over previous
//
#include <hip/hip_runtime.h>

// B=512, P=64, K=8, D=512, T=50000
// out: [B*P, 2*D] fp32
#define BB 512
#define PP 64
#define KK 8
#define DD 512

typedef float v4f __attribute__((ext_vector_type(4)));

// ---------------------------------------------------------------------------
// Fused, latency-optimized (MLP-first) kernel. One wave per output row.
//
// Round-0 version had VGPR_Count=28: the 32 gather loads per wave ran as a
// serialized chain of HBM round-trips (latency-bound: 3.5 TB/s, VALU 19%).
// Round-1/2 two-phase split regressed (extra launch + device drain + lost
// overlap beat the L3-residency gain).
//
// This version issues ALL loads up front before any arithmetic:
//   - focal row           (2 x float4 / lane)
//   - 8 neighbor rows     (16 x float4 / lane)   [masked -> focal row, L1-hot]
//   - 8 title rows        (16 x float4 / lane)   [masked -> title row 0]
// Title addresses depend only on the indices, NOT on the softmax, so the
// title gathers overlap the dot-product/softmax latency. ~34 KB in flight
// per wave; the compiler's counted s_waitcnt consumes results in order.
// VGPR goes to ~180 (3 waves/SIMD) -- in-flight bytes per CU still >250 KB,
// which is far past HBM saturation per Little's law.
// ---------------------------------------------------------------------------
__global__ __launch_bounds__(256) void han_meta_kernel(
    const float* __restrict__ inputs,       // [B,P,D]
    const float* __restrict__ title,        // [T,D]
    const int*   __restrict__ nbr_batch,    // [B,P,K]
    const int*   __restrict__ nbr_job,      // [B,P,K]
    const int*   __restrict__ nbr_title,    // [B,P,K]
    const int*   __restrict__ nbr_mask,     // [B,P,K]
    float*       __restrict__ out)          // [B*P, 2*D]
{
    const int lane = threadIdx.x & 63;
    const int wave = threadIdx.x >> 6;
    const int row  = blockIdx.x * 4 + wave;        // in [0, B*P)

    // ---- neighbor indices: 8 contiguous ints per row, 16B-aligned ----
    const int4* nb4 = (const int4*)(nbr_batch + row * KK);
    const int4* nj4 = (const int4*)(nbr_job   + row * KK);
    const int4* nt4 = (const int4*)(nbr_title + row * KK);
    const int4* nm4 = (const int4*)(nbr_mask  + row * KK);
    int nbk[KK], njk[KK], ntk[KK], nmk[KK];
    *(int4*)&nbk[0] = nb4[0]; *(int4*)&nbk[4] = nb4[1];
    *(int4*)&njk[0] = nj4[0]; *(int4*)&njk[4] = nj4[1];
    *(int4*)&ntk[0] = nt4[0]; *(int4*)&ntk[4] = nt4[1];
    *(int4*)&nmk[0] = nm4[0]; *(int4*)&nmk[4] = nm4[1];

    // ---- gather addresses (predicated, no branches; always in-bounds) ----
    const float4* g4[KK];   // neighbor job rows; masked -> focal row (L1-hot)
    const float4* t4[KK];   // title rows;        masked -> row 0 (L2-hot)
    #pragma unroll
    for (int k = 0; k < KK; ++k) {
        const size_t rg = nmk[k] ? ((size_t)nbk[k] * PP + (size_t)njk[k])
                                 : (size_t)row;
        g4[k] = (const float4*)(inputs + rg * DD);
        const size_t rt = nmk[k] ? (size_t)ntk[k] : (size_t)0;
        t4[k] = (const float4*)(title + rt * DD);
    }

    // ---- issue ALL loads before any arithmetic ----
    const float4* inp4 = (const float4*)(inputs + (size_t)row * DD);
    const float4 fa = inp4[lane];        // d = lane*4
    const float4 fb = inp4[lane + 64];   // d = 256 + lane*4
    float4 ga[KK], gb[KK];
    #pragma unroll
    for (int k = 0; k < KK; ++k) {
        ga[k] = g4[k][lane];
        gb[k] = g4[k][lane + 64];
    }
    float4 ta[KK], tb[KK];
    #pragma unroll
    for (int k = 0; k < KK; ++k) {
        ta[k] = t4[k][lane];
        tb[k] = t4[k][lane + 64];
    }

    // ---- per-lane partial dots (consumes ga/gb, frees those VGPRs) ----
    float d[KK];
    #pragma unroll
    for (int k = 0; k < KK; ++k) {
        d[k] = fa.x*ga[k].x + fa.y*ga[k].y + fa.z*ga[k].z + fa.w*ga[k].w
             + fb.x*gb[k].x + fb.y*gb[k].y + fb.z*gb[k].z + fb.w*gb[k].w;
    }

    // ---- butterfly reduce all 8 dots together (title loads still in flight)
    #pragma unroll
    for (int off = 32; off >= 1; off >>= 1) {
        #pragma unroll
        for (int k = 0; k < KK; ++k)
            d[k] += __shfl_xor(d[k], off, 64);
    }

    // ---- masked softmax over K=8 (replicated per lane; all scalar) ----
    float logit[KK];
    #pragma unroll
    for (int k = 0; k < KK; ++k) logit[k] = nmk[k] ? d[k] : -1e9f;
    float m = logit[0];
    #pragma unroll
    for (int k = 1; k < KK; ++k) m = fmaxf(m, logit[k]);
    float e[KK];
    float s = 0.0f;
    #pragma unroll
    for (int k = 0; k < KK; ++k) {
        e[k] = expf(logit[k] - m);
        s += e[k];
    }
    const float inv = 1.0f / s;
    float w[KK];
    #pragma unroll
    for (int k = 0; k < KK; ++k) w[k] = nmk[k] ? e[k] * inv : 0.0f;

    // ---- weighted title sum (w==0 exactly on masked; 0*finite == 0) ----
    float4 oa = make_float4(0.f, 0.f, 0.f, 0.f);
    float4 ob = make_float4(0.f, 0.f, 0.f, 0.f);
    #pragma unroll
    for (int k = 0; k < KK; ++k) {
        oa.x += w[k]*ta[k].x; oa.y += w[k]*ta[k].y;
        oa.z += w[k]*ta[k].z; oa.w += w[k]*ta[k].w;
        ob.x += w[k]*tb[k].x; ob.y += w[k]*tb[k].y;
        ob.z += w[k]*tb[k].z; ob.w += w[k]*tb[k].w;
    }

    // ---- write: [focal(512) | graph(512)] -- non-temporal (write-once) ----
    v4f* o4 = (v4f*)(out + (size_t)row * (2 * DD));
    v4f va = {fa.x, fa.y, fa.z, fa.w};
    v4f vb = {fb.x, fb.y, fb.z, fb.w};
    v4f vc = {oa.x, oa.y, oa.z, oa.w};
    v4f vd = {ob.x, ob.y, ob.z, ob.w};
    __builtin_nontemporal_store(va, o4 + lane);        // d 0..255
    __builtin_nontemporal_store(vb, o4 + lane + 64);   // d 256..511
    __builtin_nontemporal_store(vc, o4 + lane + 128);  // graph 0..255
    __builtin_nontemporal_store(vd, o4 + lane + 192);  // graph 256..511
}

extern "C" void kernel_launch(void* const* d_in, const int* in_sizes, int n_in,
                              void* d_out, int out_size, void* d_ws, size_t ws_size,
                              hipStream_t stream) {
    const float* inputs    = (const float*)d_in[0];
    const float* title     = (const float*)d_in[1];
    const int*   nbr_batch = (const int*)d_in[2];
    const int*   nbr_job   = (const int*)d_in[3];
    const int*   nbr_title = (const int*)d_in[4];
    const int*   nbr_mask  = (const int*)d_in[5];
    float*       out       = (float*)d_out;

    const int rows = BB * PP;     // 32768
    dim3 grid(rows / 4);          // 4 waves (rows) per 256-thread block
    dim3 block(256);

    han_meta_kernel<<<grid, block, 0, stream>>>(
        inputs, title, nbr_batch, nbr_job, nbr_title, nbr_mask, out);
}

// Round 4
// 296.897 us; speedup vs baseline: 1.0417x; 1.0095x over previous
//
#include <hip/hip_runtime.h>

// B=512, P=64, K=8, D=512, T=50000
// out: [B*P, 2*D] fp32
#define BB 512
#define PP 64
#define KK 8
#define DD 512

typedef float v4f __attribute__((ext_vector_type(4)));

// ---------------------------------------------------------------------------
// Fused, latency-optimized kernel. One wave per output row.
//
// Round-3 post-mortem: writing the loads-first structure in source was NOT
// enough -- VGPR_Count=36 proved the pressure-driven scheduler sank every
// gather back next to its use (serialized HBM round-trips; 3.4 TB/s, VALU
// 20%). This version forces the memory-level-parallel schedule:
//   1. __launch_bounds__(256, 2): VGPR cap 256 -> 136 live float4 load
//      results are legal (2 waves/SIMD, 8 waves/CU; ~270 KB in flight per
//      CU >> the ~10 KB Little's law needs at ~500 ns latency).
//   2. All addressing scalarized via readfirstlane (row and all 32 indices
//      are wave-uniform): index fetches become s_load, gather bases live in
//      SGPRs, loads are saddr-form with one shared lane*16 voffset -- no
//      VGPRs wasted on address pairs.
//   3. sched_barrier(0) between the load cluster and the arithmetic pins
//      the issue order: the scheduler cannot re-serialize.
// Masked slots are predicated (no branches) to an L1-hot row so all 34
// loads issue unconditionally.
// ---------------------------------------------------------------------------
__global__ __launch_bounds__(256, 2) void han_meta_kernel(
    const float* __restrict__ inputs,       // [B,P,D]
    const float* __restrict__ title,        // [T,D]
    const int*   __restrict__ nbr_batch,    // [B,P,K]
    const int*   __restrict__ nbr_job,      // [B,P,K]
    const int*   __restrict__ nbr_title,    // [B,P,K]
    const int*   __restrict__ nbr_mask,     // [B,P,K]
    float*       __restrict__ out)          // [B*P, 2*D]
{
    const int lane = threadIdx.x & 63;
    // row is identical across the wave's 64 lanes -> make it provably uniform
    const int row = __builtin_amdgcn_readfirstlane(
        blockIdx.x * 4 + (threadIdx.x >> 6));          // in [0, B*P)

    // ---- indices: wave-uniform scalar loads ----
    const int* nb = nbr_batch + row * KK;
    const int* nj = nbr_job   + row * KK;
    const int* nt = nbr_title + row * KK;
    const int* nm = nbr_mask  + row * KK;
    int nbk[KK], njk[KK], ntk[KK], nmk[KK];
    #pragma unroll
    for (int k = 0; k < KK; ++k) {
        nbk[k] = __builtin_amdgcn_readfirstlane(nb[k]);
        njk[k] = __builtin_amdgcn_readfirstlane(nj[k]);
        ntk[k] = __builtin_amdgcn_readfirstlane(nt[k]);
        nmk[k] = __builtin_amdgcn_readfirstlane(nm[k]);
    }

    // ---- scalar (SGPR) byte offsets; masked -> L1-hot safe row ----
    // inputs table is 64 MB, title table 102 MB: both fit 32-bit offsets.
    const unsigned focal_off = (unsigned)row * (DD * 4);
    unsigned goff[KK], toff[KK];
    #pragma unroll
    for (int k = 0; k < KK; ++k) {
        goff[k] = nmk[k] ? (unsigned)(nbk[k] * PP + njk[k]) * (DD * 4)
                         : focal_off;                   // focal row: L1-hot
        toff[k] = nmk[k] ? (unsigned)ntk[k] * (DD * 4)
                         : 0u;                          // title row 0: L2-hot
    }

    const char* ibase = (const char*)inputs;
    const char* tbase = (const char*)title;
    const int lo = lane * 16;      // one shared voffset for every load

    // ---- issue ALL 34 float4 loads before any arithmetic ----
    const float4 fa = *(const float4*)(ibase + focal_off + lo);
    const float4 fb = *(const float4*)(ibase + focal_off + lo + 1024);
    float4 ga[KK], gb[KK];
    #pragma unroll
    for (int k = 0; k < KK; ++k) {
        ga[k] = *(const float4*)(ibase + goff[k] + lo);
        gb[k] = *(const float4*)(ibase + goff[k] + lo + 1024);
    }
    float4 ta[KK], tb[KK];
    #pragma unroll
    for (int k = 0; k < KK; ++k) {
        ta[k] = *(const float4*)(tbase + toff[k] + lo);
        tb[k] = *(const float4*)(tbase + toff[k] + lo + 1024);
    }
    // pin the schedule: nothing below may be hoisted above, nothing above
    // (the load cluster) may be sunk below.
    __builtin_amdgcn_sched_barrier(0);

    // ---- per-lane partial dots (counted waitcnt: titles stay in flight) ----
    float d[KK];
    #pragma unroll
    for (int k = 0; k < KK; ++k) {
        d[k] = fa.x*ga[k].x + fa.y*ga[k].y + fa.z*ga[k].z + fa.w*ga[k].w
             + fb.x*gb[k].x + fb.y*gb[k].y + fb.z*gb[k].z + fb.w*gb[k].w;
    }

    // ---- butterfly reduce all 8 dots together ----
    #pragma unroll
    for (int off = 32; off >= 1; off >>= 1) {
        #pragma unroll
        for (int k = 0; k < KK; ++k)
            d[k] += __shfl_xor(d[k], off, 64);
    }

    // ---- masked softmax over K=8 (replicated per lane; all scalar) ----
    float logit[KK];
    #pragma unroll
    for (int k = 0; k < KK; ++k) logit[k] = nmk[k] ? d[k] : -1e9f;
    float m = logit[0];
    #pragma unroll
    for (int k = 1; k < KK; ++k) m = fmaxf(m, logit[k]);
    float e[KK];
    float s = 0.0f;
    #pragma unroll
    for (int k = 0; k < KK; ++k) {
        e[k] = expf(logit[k] - m);
        s += e[k];
    }
    const float inv = 1.0f / s;
    float w[KK];
    #pragma unroll
    for (int k = 0; k < KK; ++k) w[k] = nmk[k] ? e[k] * inv : 0.0f;

    // ---- weighted title sum (w==0 exactly on masked; 0*finite == 0) ----
    float4 oa = make_float4(0.f, 0.f, 0.f, 0.f);
    float4 ob = make_float4(0.f, 0.f, 0.f, 0.f);
    #pragma unroll
    for (int k = 0; k < KK; ++k) {
        oa.x += w[k]*ta[k].x; oa.y += w[k]*ta[k].y;
        oa.z += w[k]*ta[k].z; oa.w += w[k]*ta[k].w;
        ob.x += w[k]*tb[k].x; ob.y += w[k]*tb[k].y;
        ob.z += w[k]*tb[k].z; ob.w += w[k]*tb[k].w;
    }

    // ---- write: [focal(512) | graph(512)] -- non-temporal (write-once) ----
    v4f* o4 = (v4f*)(out + (size_t)row * (2 * DD));
    v4f va = {fa.x, fa.y, fa.z, fa.w};
    v4f vb = {fb.x, fb.y, fb.z, fb.w};
    v4f vc = {oa.x, oa.y, oa.z, oa.w};
    v4f vd = {ob.x, ob.y, ob.z, ob.w};
    __builtin_nontemporal_store(va, o4 + lane);        // d 0..255
    __builtin_nontemporal_store(vb, o4 + lane + 64);   // d 256..511
    __builtin_nontemporal_store(vc, o4 + lane + 128);  // graph 0..255
    __builtin_nontemporal_store(vd, o4 + lane + 192);  // graph 256..511
}

extern "C" void kernel_launch(void* const* d_in, const int* in_sizes, int n_in,
                              void* d_out, int out_size, void* d_ws, size_t ws_size,
                              hipStream_t stream) {
    const float* inputs    = (const float*)d_in[0];
    const float* title     = (const float*)d_in[1];
    const int*   nbr_batch = (const int*)d_in[2];
    const int*   nbr_job   = (const int*)d_in[3];
    const int*   nbr_title = (const int*)d_in[4];
    const int*   nbr_mask  = (const int*)d_in[5];
    float*       out       = (float*)d_out;

    const int rows = BB * PP;     // 32768
    dim3 grid(rows / 4);          // 4 waves (rows) per 256-thread block
    dim3 block(256);

    han_meta_kernel<<<grid, block, 0, stream>>>(
        inputs, title, nbr_batch, nbr_job, nbr_title, nbr_mask, out);
}